// Round 9
// baseline (500.386 us; speedup 1.0000x reference)
//
#include <hip/hip_runtime.h>

#define HH 20
#define WW 20
#define TT 96
#define BB 64
#define SIG 306
#define NFC 17
#define TSTRIDE 264    // feat per-t stride: 4b*4pix*16ch + 8 pad
#define CHUNK 16
#define NCHUNK 6
#define XTS 65         // xs per-(b,t) stride: 4ci*16 + 1
#define XBS (CHUNK * XTS)   // per-b xs block = 1040 floats

typedef float float4u __attribute__((ext_vector_type(4), aligned(4)));

// ---------------------------------------------------------------------------
// Kernel 1: conv + signature + fused MLP-1 (sig never touches HBM).
// Block = 256 thr (4 waves) = (2x2-pixel tile, 4 batches); wave = one batch.
// Grid = 100 tiles * 16 b-groups = 1600. lane = (b_local, pix, tt | ij-tile).
// Phase-2 telescoped: core = 0.5*accv' - f0_i*lvl1_j (validated r7/r8).
// Epilogue: each lane FMAs its sig values against w1 rows (L2-cached across
// the 16 b-group blocks of a tile), wave-reduce, 32 atomicAdds per wave.
// ---------------------------------------------------------------------------
__global__ __launch_bounds__(256) void sig_fused(
    const float* __restrict__ x,    // (64,96,4,20,20)
    const float* __restrict__ cw,   // (12,4,3,3)
    const float* __restrict__ w1,   // (122400,32)
    float* __restrict__ acc)        // (64,32) zeroed
{
  __shared__ __align__(16) float feat[CHUNK * TSTRIDE];   // 16.5 KB
  __shared__ __align__(16) float xs[4 * XBS];             // 16.6 KB
  __shared__ __align__(16) float wlds[12 * 48];           // [k][ci][dy][4]

  const int tid = threadIdx.x;
  const int blk = blockIdx.x;
  const int tile = blk >> 4;          // 0..99
  const int bg   = blk & 15;          // b-group (fast index -> w1 L2 reuse)
  const int th2 = (tile / 10) * 2, tw2 = (tile % 10) * 2;

  // ---- stage conv weights (bias dropped: signature bias-invariant) ----
  #pragma unroll
  for (int r = 0; r < 3; r++) {
    int idx = r * 256 + tid;
    if (idx < 576) {
      int k = idx / 48, rem = idx % 48;
      int ci = rem / 12, r2 = rem % 12, dy = r2 >> 2, dx = r2 & 3;
      wlds[idx] = (dx < 3) ? cw[k * 36 + ci * 9 + dy * 3 + dx] : 0.f;
    }
  }

  // ---- staging precompute: 4096 halo values/chunk = 16/thread (4 rr x 4 b) ----
  int goff[4], loff[4];
  #pragma unroll
  for (int rr = 0; rr < 4; rr++) {
    int inner = rr * 256 + tid;          // < 1024
    int t = inner >> 6, s2 = inner & 63;
    int ci = s2 >> 4, pos = s2 & 15;
    int pr = pos >> 2, pc = pos & 3;
    int gr = th2 - 1 + pr, gc = tw2 - 1 + pc;
    bool valid = (gr >= 0 && gr < HH && gc >= 0 && gc < WW);
    goff[rr] = valid ? (t * 1600 + ci * 400 + gr * WW + gc) : -1;
    loff[rr] = t * XTS + ci * 16 + pos;
  }

  // ---- lane maps ----
  const int bl  = tid >> 6;            // b_local = wave index
  const int pix = (tid >> 4) & 3;      // pixel in 2x2 tile
  const int ctt = tid & 15;            // conv: t within chunk
  const int cpy = pix >> 1, cpx = pix & 1;
  const int rr2 = tid & 15, it = rr2 >> 2, jt = rr2 & 3;
  const int i0 = it * 4, j0 = jt * 4;

  float accv[4][4];
  float f0a[4], f0b[4], pa[4], pb[4], fsum[4];
  #pragma unroll
  for (int i = 0; i < 4; i++)
    #pragma unroll
    for (int j = 0; j < 4; j++) accv[i][j] = 0.f;

  auto stage = [&](int chunk) {
    const float* xc = x + (size_t)chunk * CHUNK * 1600;
    float rg[16];
    #pragma unroll
    for (int bb = 0; bb < 4; bb++) {
      const float* xbp = xc + (size_t)(bg * 4 + bb) * TT * 1600;
      #pragma unroll
      for (int rr = 0; rr < 4; rr++)
        rg[bb * 4 + rr] = (goff[rr] >= 0) ? xbp[goff[rr]] : 0.f;
    }
    #pragma unroll
    for (int bb = 0; bb < 4; bb++)
      #pragma unroll
      for (int rr = 0; rr < 4; rr++)
        xs[bb * XBS + loff[rr]] = rg[bb * 4 + rr];
  };

  auto conv = [&]() {
    float win[4][9];
    const int wb2 = bl * XBS + ctt * XTS;
    #pragma unroll
    for (int ci = 0; ci < 4; ci++)
      #pragma unroll
      for (int dy = 0; dy < 3; dy++)
        #pragma unroll
        for (int dxx = 0; dxx < 3; dxx++)
          win[ci][dy * 3 + dxx] = xs[wb2 + ci * 16 + (cpy + dy) * 4 + (cpx + dxx)];

    float fk[12];
    #pragma unroll
    for (int k = 0; k < 12; k++) {
      float a = 0.f;
      #pragma unroll
      for (int ci = 0; ci < 4; ci++) {
        #pragma unroll
        for (int dy = 0; dy < 3; dy++) {
          const float4 w4 = *reinterpret_cast<const float4*>(
              &wlds[k * 48 + ci * 12 + dy * 4]);
          a += win[ci][dy * 3 + 0] * w4.x + win[ci][dy * 3 + 1] * w4.y +
               win[ci][dy * 3 + 2] * w4.z;
        }
      }
      fk[k] = a;
    }
    float* fr = &feat[ctt * TSTRIDE + bl * 64 + pix * 16];
    *reinterpret_cast<float4*>(fr + 0)  = make_float4(fk[0], fk[1], fk[2], fk[3]);
    *reinterpret_cast<float4*>(fr + 4)  = make_float4(fk[4], fk[5], fk[6], fk[7]);
    *reinterpret_cast<float4*>(fr + 8)  = make_float4(fk[8], fk[9], fk[10], fk[11]);
    *reinterpret_cast<float4*>(fr + 12) = make_float4(win[0][4], win[1][4], win[2][4], win[3][4]);
  };

  auto p2step = [&](int tt) {
    const float* row = &feat[tt * TSTRIDE + bl * 64 + pix * 16];
    const float4 a4 = *reinterpret_cast<const float4*>(row + i0);
    const float4 b4 = *reinterpret_cast<const float4*>(row + j0);
    float fa[4] = {a4.x, a4.y, a4.z, a4.w};
    float fb[4] = {b4.x, b4.y, b4.z, b4.w};
    float sa[4], db[4];
    #pragma unroll
    for (int i = 0; i < 4; i++) { sa[i] = fa[i] + pa[i]; db[i] = fb[i] - pb[i]; }
    #pragma unroll
    for (int i = 0; i < 4; i++)
      #pragma unroll
      for (int j = 0; j < 4; j++) accv[i][j] += sa[i] * db[j];
    #pragma unroll
    for (int i = 0; i < 4; i++) { fsum[i] += fa[i]; pa[i] = fa[i]; pb[i] = fb[i]; }
  };

  // ===== chunk 0 (peeled) =====
  stage(0);
  __syncthreads();
  conv();
  __syncthreads();
  {
    const float* r0 = &feat[bl * 64 + pix * 16];
    const float4 a4 = *reinterpret_cast<const float4*>(r0 + i0);
    const float4 b4 = *reinterpret_cast<const float4*>(r0 + j0);
    f0a[0] = a4.x; f0a[1] = a4.y; f0a[2] = a4.z; f0a[3] = a4.w;
    f0b[0] = b4.x; f0b[1] = b4.y; f0b[2] = b4.z; f0b[3] = b4.w;
    #pragma unroll
    for (int i = 0; i < 4; i++) { pa[i] = f0a[i]; pb[i] = f0b[i]; fsum[i] = f0a[i]; }
  }
  #pragma unroll
  for (int tt = 1; tt < CHUNK; tt++) p2step(tt);

  // ===== chunks 1..5 =====
  for (int chunk = 1; chunk < NCHUNK; chunk++) {
    __syncthreads();
    stage(chunk);
    __syncthreads();
    conv();
    __syncthreads();
    #pragma unroll
    for (int tt = 0; tt < CHUNK; tt++) p2step(tt);
  }

  // ===== fused MLP-1 epilogue =====
  float mlp[32];
  #pragma unroll
  for (int n = 0; n < 32; n++) mlp[n] = 0.f;

  {
    const int pg = (th2 + (pix >> 1)) * WW + (tw2 + (pix & 1));
    const float* wb1 = w1 + (size_t)pg * SIG * 32;

    auto fma_row = [&](int row, float sv) {
      const float4* wp = reinterpret_cast<const float4*>(wb1 + (size_t)row * 32);
      #pragma unroll
      for (int q = 0; q < 8; q++) {
        float4 w = wp[q];
        mlp[q * 4 + 0] += sv * w.x; mlp[q * 4 + 1] += sv * w.y;
        mlp[q * 4 + 2] += sv * w.z; mlp[q * 4 + 3] += sv * w.w;
      }
    };

    float lv1b[4];
    #pragma unroll
    for (int j = 0; j < 4; j++) lv1b[j] = pb[j] - f0b[j];

    // 16 core lvl2 rows
    #pragma unroll
    for (int ii = 0; ii < 4; ii++)
      #pragma unroll
      for (int jj = 0; jj < 4; jj++)
        fma_row(NFC + (i0 + ii) * NFC + (j0 + jj),
                0.5f * accv[ii][jj] - f0a[ii] * lv1b[jj]);

    // analytic extras on jt==0 lanes
    if (jt == 0) {
      #pragma unroll
      for (int ii = 0; ii < 4; ii++) {
        const int c = i0 + ii;
        const float f0 = f0a[ii], f95 = pa[ii], fs = fsum[ii];
        fma_row(c, f95 - f0);                                          // lvl1
        fma_row(NFC + c * NFC + 16, (fs - 95.5f * f0 - 0.5f * f95) * (1.f / 95.f));
        fma_row(NFC + 16 * NFC + c, (95.5f * f95 + 0.5f * f0 - fs) * (1.f / 95.f));
      }
      if (it == 0) {
        fma_row(16, 1.0f);                    // lvl1 tch
        fma_row(NFC + 16 * NFC + 16, 0.5f);   // lvl2 tch corner
      }
    }
  }

  // wave-reduce (wave = one b) + 32 atomics per wave
  const int bglob = bg * 4 + bl;
  #pragma unroll
  for (int n = 0; n < 32; n++) {
    float v = mlp[n];
    #pragma unroll
    for (int o = 32; o >= 1; o >>= 1) v += __shfl_xor(v, o, 64);
    if ((tid & 63) == 0) atomicAdd(&acc[bglob * 32 + n], v);
  }
}

// ---------------------------------------------------------------------------
// Kernel 2: MLP layers 2-4. 64 blocks (one per b); lanes 0..31 of wave 0.
// ---------------------------------------------------------------------------
__global__ __launch_bounds__(64) void mlp_tail(
    const float* __restrict__ acc, const float* __restrict__ b1,
    const float* __restrict__ w2, const float* __restrict__ b2,
    const float* __restrict__ w3, const float* __restrict__ b3,
    const float* __restrict__ w4, const float* __restrict__ b4,
    float* __restrict__ out)
{
  const int n = threadIdx.x & 31;
  const int b = blockIdx.x;
  if (threadIdx.x >= 32) return;

  float h = fmaxf(acc[b * 32 + n] + b1[n], 0.f);

  float v = b2[n];
  #pragma unroll
  for (int k = 0; k < 32; k++)
    v += __shfl(h, k, 64) * w2[k * 32 + n];
  h = fmaxf(v, 0.f);

  v = b3[n];
  #pragma unroll
  for (int k = 0; k < 32; k++)
    v += __shfl(h, k, 64) * w3[k * 32 + n];
  h = fmaxf(v, 0.f);

  float p = h * w4[n];
  #pragma unroll
  for (int o = 16; o >= 1; o >>= 1) p += __shfl_xor(p, o, 64);
  if (n == 0) out[b] = p + b4[0];
}

extern "C" void kernel_launch(void* const* d_in, const int* in_sizes, int n_in,
                              void* d_out, int out_size, void* d_ws, size_t ws_size,
                              hipStream_t stream) {
  const float* x  = (const float*)d_in[0];
  const float* cw = (const float*)d_in[1];
  const float* w1 = (const float*)d_in[3];
  const float* b1 = (const float*)d_in[4];
  const float* w2 = (const float*)d_in[5];
  const float* b2 = (const float*)d_in[6];
  const float* w3 = (const float*)d_in[7];
  const float* b3 = (const float*)d_in[8];
  const float* w4 = (const float*)d_in[9];
  const float* b4 = (const float*)d_in[10];
  float* out = (float*)d_out;
  float* acc = (float*)d_ws;   // 64*32 fp32 = 8 KB

  hipMemsetAsync(acc, 0, BB * 32 * sizeof(float), stream);
  sig_fused<<<dim3(1600), dim3(256), 0, stream>>>(x, cw, w1, acc);
  mlp_tail<<<dim3(64), dim3(64), 0, stream>>>(acc, b1, w2, b2, w3, b3, w4, b4, out);
}

// Round 10
// 264.703 us; speedup vs baseline: 1.8904x; 1.8904x over previous
//
#include <hip/hip_runtime.h>

#define HH 20
#define WW 20
#define TT 96
#define BB 64
#define SIG 306
#define NFC 17
#define TSTRIDE 264    // feat per-t stride: 16pix*16ch + 8 (bank de-alias)
#define CHUNK 16
#define NCHUNK 6
#define XT 199         // xs per-t stride
#define KTOT 122400
#define LDT 68         // ldsT row stride (16B-aligned float4 rows)

typedef float float4u __attribute__((ext_vector_type(4), aligned(4)));

// ---------------------------------------------------------------------------
// Kernel 1: conv + signature -> sig workspace. (FROZEN r7/r8 source: 144 us)
// Block = 256 thr (4 waves) = one (b, 4x4-pixel tile). Grid 64*25 = 1600.
// Phase-2 telescoped: core = 0.5*accv' - f0_i*lvl1_j.
// ---------------------------------------------------------------------------
__global__ __launch_bounds__(256) void sig_kernel(
    const float* __restrict__ x,    // (64,96,4,20,20)
    const float* __restrict__ cw,   // (12,4,3,3)
    float* __restrict__ sig)        // (64,122400)
{
  __shared__ __align__(16) float feat[15 * TSTRIDE + 256 + 8];
  __shared__ __align__(16) float xs[CHUNK * XT];
  __shared__ __align__(16) float wlds[12 * 48];   // [k][ci][dy][4]

  const int tid = threadIdx.x;
  const int blk = blockIdx.x;
  const int b = blk / 25;
  const int tile = blk % 25;
  const int th4 = (tile / 5) * 4, tw4 = (tile % 5) * 4;
  const float* xb0 = x + (size_t)b * TT * 1600;

  #pragma unroll
  for (int r = 0; r < 3; r++) {
    int idx = r * 256 + tid;
    if (idx < 576) {
      int k = idx / 48, rem = idx % 48;
      int ci = rem / 12, r2 = rem % 12, dy = r2 >> 2, dx = r2 & 3;
      wlds[idx] = (dx < 3) ? cw[k * 36 + ci * 9 + dy * 3 + dx] : 0.f;
    }
  }

  int g_off[9], l_off[9];
  #pragma unroll
  for (int r = 0; r < 9; r++) {
    int idx = r * 256 + tid;
    int t = idx / 144, q = idx % 144;
    int ci = q / 36, pos = q % 36, row = pos / 6, col = pos % 6;
    int gr = th4 - 1 + row, gc = tw4 - 1 + col;
    bool valid = (gr >= 0 && gr < HH && gc >= 0 && gc < WW);
    g_off[r] = valid ? (t * 1600 + ci * 400 + gr * WW + gc) : -1;
    l_off[r] = t * XT + ci * 48 + row * 8 + col;
  }

  const int cpix = tid >> 4, ctt = tid & 15;
  const int cpy = cpix >> 2, cpx = cpix & 3;

  const int p2 = tid >> 4;
  const int rr = tid & 15, it = rr >> 2, jt = rr & 3;
  const int i0 = it * 4, j0 = jt * 4;

  float accv[4][4];
  float f0a[4], f0b[4], pa[4], pb[4], fsum[4];
  #pragma unroll
  for (int i = 0; i < 4; i++) {
    #pragma unroll
    for (int j = 0; j < 4; j++) accv[i][j] = 0.f;
  }

  auto stage = [&](int chunk) {
    const float* xbc = xb0 + (size_t)chunk * CHUNK * 1600;
    float rg[9];
    #pragma unroll
    for (int r = 0; r < 9; r++)
      rg[r] = (g_off[r] >= 0) ? xbc[g_off[r]] : 0.f;
    #pragma unroll
    for (int r = 0; r < 9; r++) xs[l_off[r]] = rg[r];
  };

  auto conv = [&]() {
    float win[4][9];
    const int wb2 = ctt * XT;
    #pragma unroll
    for (int ci = 0; ci < 4; ci++)
      #pragma unroll
      for (int dy = 0; dy < 3; dy++)
        #pragma unroll
        for (int dxx = 0; dxx < 3; dxx++)
          win[ci][dy * 3 + dxx] = xs[wb2 + ci * 48 + (cpy + dy) * 8 + (cpx + dxx)];

    float fk[12];
    #pragma unroll
    for (int k = 0; k < 12; k++) {
      float a = 0.f;
      #pragma unroll
      for (int ci = 0; ci < 4; ci++) {
        #pragma unroll
        for (int dy = 0; dy < 3; dy++) {
          const float4 w4 = *reinterpret_cast<const float4*>(
              &wlds[k * 48 + ci * 12 + dy * 4]);
          a += win[ci][dy * 3 + 0] * w4.x + win[ci][dy * 3 + 1] * w4.y +
               win[ci][dy * 3 + 2] * w4.z;
        }
      }
      fk[k] = a;
    }
    float* fr = &feat[ctt * TSTRIDE + cpix * 16];
    *reinterpret_cast<float4*>(fr + 0)  = make_float4(fk[0], fk[1], fk[2], fk[3]);
    *reinterpret_cast<float4*>(fr + 4)  = make_float4(fk[4], fk[5], fk[6], fk[7]);
    *reinterpret_cast<float4*>(fr + 8)  = make_float4(fk[8], fk[9], fk[10], fk[11]);
    *reinterpret_cast<float4*>(fr + 12) = make_float4(win[0][4], win[1][4], win[2][4], win[3][4]);
  };

  auto p2step = [&](int tt) {
    const float* row = &feat[tt * TSTRIDE + p2 * 16];
    const float4 a4 = *reinterpret_cast<const float4*>(row + i0);
    const float4 b4 = *reinterpret_cast<const float4*>(row + j0);
    float fa[4] = {a4.x, a4.y, a4.z, a4.w};
    float fb[4] = {b4.x, b4.y, b4.z, b4.w};
    float sa[4], db[4];
    #pragma unroll
    for (int i = 0; i < 4; i++) { sa[i] = fa[i] + pa[i]; db[i] = fb[i] - pb[i]; }
    #pragma unroll
    for (int i = 0; i < 4; i++)
      #pragma unroll
      for (int j = 0; j < 4; j++) accv[i][j] += sa[i] * db[j];
    #pragma unroll
    for (int i = 0; i < 4; i++) { fsum[i] += fa[i]; pa[i] = fa[i]; pb[i] = fb[i]; }
  };

  // ===== chunk 0 (peeled) =====
  stage(0);
  __syncthreads();
  conv();
  __syncthreads();
  {
    const float* r0 = &feat[p2 * 16];
    const float4 a4 = *reinterpret_cast<const float4*>(r0 + i0);
    const float4 b4 = *reinterpret_cast<const float4*>(r0 + j0);
    f0a[0] = a4.x; f0a[1] = a4.y; f0a[2] = a4.z; f0a[3] = a4.w;
    f0b[0] = b4.x; f0b[1] = b4.y; f0b[2] = b4.z; f0b[3] = b4.w;
    #pragma unroll
    for (int i = 0; i < 4; i++) { pa[i] = f0a[i]; pb[i] = f0b[i]; fsum[i] = f0a[i]; }
  }
  #pragma unroll
  for (int tt = 1; tt < CHUNK; tt++) p2step(tt);

  // ===== chunks 1..5 =====
  for (int chunk = 1; chunk < NCHUNK; chunk++) {
    __syncthreads();
    stage(chunk);
    __syncthreads();
    conv();
    __syncthreads();
    #pragma unroll
    for (int tt = 0; tt < CHUNK; tt++) p2step(tt);
  }

  // ===== write sig =====
  {
    const int ph = th4 + (p2 >> 2), pw = tw4 + (p2 & 3);
    float* sb = sig + (size_t)b * KTOT + (size_t)(ph * WW + pw) * SIG;
    float lv1b[4];
    #pragma unroll
    for (int j = 0; j < 4; j++) lv1b[j] = pb[j] - f0b[j];
    #pragma unroll
    for (int ii = 0; ii < 4; ii++) {
      float4u v;
      #pragma unroll
      for (int jj = 0; jj < 4; jj++)
        v[jj] = 0.5f * accv[ii][jj] - f0a[ii] * lv1b[jj];
      *reinterpret_cast<float4u*>(sb + NFC + (i0 + ii) * NFC + j0) = v;
    }
    if (jt == 0) {
      #pragma unroll
      for (int ii = 0; ii < 4; ii++) {
        const int c = i0 + ii;
        const float f0 = f0a[ii], f95 = pa[ii], fs = fsum[ii];
        sb[c] = f95 - f0;                                            // lvl1
        sb[NFC + c * NFC + 16] = (fs - 95.5f * f0 - 0.5f * f95) * (1.f / 95.f);
        sb[NFC + 16 * NFC + c] = (95.5f * f95 + 0.5f * f0 - fs) * (1.f / 95.f);
      }
      if (it == 0) { sb[16] = 1.0f; sb[NFC + 16 * NFC + 16] = 0.5f; }
    }
  }
}

// ---------------------------------------------------------------------------
// Kernel 2: MLP-1 K-split GEMM v2.
// Thread = (n-pair, b-quad): per kk = 1 ds_read_b128 (4 sig) + 1 global
// float2 (2 w1, coalesced) + 8 FMA. No wls LDS buffer (VMEM pipe was idle),
// LDS 32.6 KB -> 4 blocks/CU; primary grid 1020 x 1 slab = 16 waves/CU.
// Partials written [b*32+n][blk] (stride pstride) for a coalesced tail.
// ---------------------------------------------------------------------------
__global__ __launch_bounds__(256) void mlp1_gemm2(
    const float* __restrict__ sig, const float* __restrict__ w1,
    float* __restrict__ part, int nslab, int pstride)
{
  __shared__ __align__(16) float ldsT[120 * LDT];   // [k][b] 32.6 KB
  const int tid = threadIdx.x;
  const int np = tid & 15;     // n = np*2 + {0,1}
  const int bq = tid >> 4;     // b = bq*4 + {0..3}

  float a2[2][4];
  #pragma unroll
  for (int j = 0; j < 2; j++)
    #pragma unroll
    for (int i = 0; i < 4; i++) a2[j][i] = 0.f;

  for (int s = 0; s < nslab; s++) {
    const int k0 = (blockIdx.x * nslab + s) * 120;
    if (s) __syncthreads();
    #pragma unroll
    for (int r = 0; r < 30; r++) {             // 64*120/256
      int idx = r * 256 + tid;
      int b = idx / 120, kk = idx % 120;
      ldsT[kk * LDT + b] = sig[(size_t)b * KTOT + k0 + kk];
    }
    __syncthreads();

    const float* w1p = w1 + (size_t)k0 * 32 + np * 2;
    #pragma unroll 8
    for (int kk = 0; kk < 120; kk++) {
      const float2 w = *reinterpret_cast<const float2*>(w1p + (size_t)kk * 32);
      const float4 sv = *reinterpret_cast<const float4*>(&ldsT[kk * LDT + bq * 4]);
      a2[0][0] += w.x * sv.x; a2[0][1] += w.x * sv.y;
      a2[0][2] += w.x * sv.z; a2[0][3] += w.x * sv.w;
      a2[1][0] += w.y * sv.x; a2[1][1] += w.y * sv.y;
      a2[1][2] += w.y * sv.z; a2[1][3] += w.y * sv.w;
    }
  }

  #pragma unroll
  for (int j = 0; j < 2; j++)
    #pragma unroll
    for (int i = 0; i < 4; i++)
      part[(size_t)((bq * 4 + i) * 32 + np * 2 + j) * pstride + blockIdx.x] = a2[j][i];
}

// ---------------------------------------------------------------------------
// Kernel 3: partial-reduce + MLP layers 2-4. 64 blocks (one per b) x 256 thr.
// Thread (s,n) sums a CONTIGUOUS segment of part[(b*32+n)][:] via float4.
// ---------------------------------------------------------------------------
__global__ __launch_bounds__(256) void mlp_tail2(
    const float* __restrict__ part, int nkb, int pstride,
    const float* __restrict__ b1,
    const float* __restrict__ w2, const float* __restrict__ b2,
    const float* __restrict__ w3, const float* __restrict__ b3,
    const float* __restrict__ w4, const float* __restrict__ b4,
    float* __restrict__ out)
{
  __shared__ float red[8][33];
  const int tid = threadIdx.x;
  const int n = tid & 31;
  const int s = tid >> 5;            // 0..7
  const int b = blockIdx.x;

  const float* pp = part + (size_t)(b * 32 + n) * pstride;
  const int seg = (nkb + 7) >> 3;
  const int k0 = s * seg;
  const int k1 = (k0 + seg < nkb) ? (k0 + seg) : nkb;

  float sum = 0.f;
  int k = k0;
  #pragma unroll 4
  for (; k + 3 < k1; k += 4) {
    const float4 v = *reinterpret_cast<const float4*>(pp + k);
    sum += v.x + v.y + v.z + v.w;
  }
  for (; k < k1; k++) sum += pp[k];
  red[s][n] = sum;
  __syncthreads();

  if (tid < 32) {
    float acc = red[0][n];
    #pragma unroll
    for (int q = 1; q < 8; q++) acc += red[q][n];

    float h = fmaxf(acc + b1[n], 0.f);

    float v = b2[n];
    #pragma unroll
    for (int k2 = 0; k2 < 32; k2++)
      v += __shfl(h, k2, 64) * w2[k2 * 32 + n];
    h = fmaxf(v, 0.f);

    v = b3[n];
    #pragma unroll
    for (int k2 = 0; k2 < 32; k2++)
      v += __shfl(h, k2, 64) * w3[k2 * 32 + n];
    h = fmaxf(v, 0.f);

    float p = h * w4[n];
    #pragma unroll
    for (int o = 16; o >= 1; o >>= 1) p += __shfl_xor(p, o, 64);
    if (n == 0) out[b] = p + b4[0];
  }
}

extern "C" void kernel_launch(void* const* d_in, const int* in_sizes, int n_in,
                              void* d_out, int out_size, void* d_ws, size_t ws_size,
                              hipStream_t stream) {
  const float* x  = (const float*)d_in[0];
  const float* cw = (const float*)d_in[1];
  const float* w1 = (const float*)d_in[3];
  const float* b1 = (const float*)d_in[4];
  const float* w2 = (const float*)d_in[5];
  const float* b2 = (const float*)d_in[6];
  const float* w3 = (const float*)d_in[7];
  const float* b3 = (const float*)d_in[8];
  const float* w4 = (const float*)d_in[9];
  const float* b4 = (const float*)d_in[10];
  float* out = (float*)d_out;

  const size_t sig_bytes = (size_t)BB * KTOT * sizeof(float);   // 31.33 MB
  float* sigm = (float*)d_ws;
  float* part = (float*)((char*)d_ws + sig_bytes);

  // primary: 1020 blocks x 120K, part stride 1024 (needs 39.73 MB total)
  // fallback: 255 blocks x 480K (4 slabs), stride 256 (33.44 MB, ws-verified)
  int nkb, nslab, pstride;
  if (ws_size >= sig_bytes + (size_t)BB * 32 * 1024 * sizeof(float)) {
    nkb = 1020; nslab = 1; pstride = 1024;
  } else {
    nkb = 255;  nslab = 4; pstride = 256;
  }

  sig_kernel<<<dim3(1600), dim3(256), 0, stream>>>(x, cw, sigm);
  mlp1_gemm2<<<dim3(nkb), dim3(256), 0, stream>>>(sigm, w1, part, nslab, pstride);
  mlp_tail2<<<dim3(64), dim3(256), 0, stream>>>(part, nkb, pstride,
                                                b1, w2, b2, w3, b3, w4, b4, out);
}